// Round 6
// baseline (82.397 us; speedup 1.0000x reference)
//
#include <hip/hip_runtime.h>

constexpr int STRU = 68;   // row stride in u32

typedef short v8s __attribute__((ext_vector_type(8)));
typedef float v4f __attribute__((ext_vector_type(4)));

// swizzled address: row i, col j. XOR bit3(i)->bit4(j): col gathers become
// conflict-free (2 lanes/bank) while rows stay b128-contiguous per 8-block.
__device__ __forceinline__ int swz(int i, int j) {
    return i * STRU + (j ^ ((i & 8) << 1));
}

// fp32 -> packed (bf16_hi << 16) | bf16_lo. hi = truncated, lo = Dekker remainder.
__device__ __forceinline__ unsigned packhl(float x) {
    unsigned xb = __builtin_bit_cast(unsigned, x);
    unsigned hb = xb & 0xffff0000u;
    float lof = x - __builtin_bit_cast(float, hb);           // exact
    unsigned lb = __builtin_bit_cast(unsigned, lof) + 0x8000u;
    return __builtin_amdgcn_perm(xb, lb, 0x07060302u);
}

__device__ __forceinline__ float unpackf(unsigned v) {
    float h = __builtin_bit_cast(float, v & 0xffff0000u);
    float l = __builtin_bit_cast(float, v << 16);
    return h + l;
}

// 8 contiguous packed u32 (row fragment) -> hi/lo bf16x8
__device__ __forceinline__ void load_frag(const unsigned* p, v8s& hi, v8s& lo) {
    uint4 a = *(const uint4*)p;
    uint4 b = *(const uint4*)(p + 4);
    uint4 hw, lw;
    hw.x = __builtin_amdgcn_perm(a.y, a.x, 0x07060302u);
    hw.y = __builtin_amdgcn_perm(a.w, a.z, 0x07060302u);
    hw.z = __builtin_amdgcn_perm(b.y, b.x, 0x07060302u);
    hw.w = __builtin_amdgcn_perm(b.w, b.z, 0x07060302u);
    lw.x = __builtin_amdgcn_perm(a.y, a.x, 0x05040100u);
    lw.y = __builtin_amdgcn_perm(a.w, a.z, 0x05040100u);
    lw.z = __builtin_amdgcn_perm(b.y, b.x, 0x05040100u);
    lw.w = __builtin_amdgcn_perm(b.w, b.z, 0x05040100u);
    hi = __builtin_bit_cast(v8s, hw);
    lo = __builtin_bit_cast(v8s, lw);
}

// column fragment: Q[kbase+j][col], j=0..7 (swizzle makes this 2 lanes/bank)
__device__ __forceinline__ void load_col_frag(const unsigned* Q, int col, int kbase,
                                              v8s& hi, v8s& lo) {
    unsigned x[8];
    #pragma unroll
    for (int j = 0; j < 8; ++j) x[j] = Q[swz(kbase + j, col)];
    uint4 hw, lw;
    hw.x = __builtin_amdgcn_perm(x[1], x[0], 0x07060302u);
    hw.y = __builtin_amdgcn_perm(x[3], x[2], 0x07060302u);
    hw.z = __builtin_amdgcn_perm(x[5], x[4], 0x07060302u);
    hw.w = __builtin_amdgcn_perm(x[7], x[6], 0x07060302u);
    lw.x = __builtin_amdgcn_perm(x[1], x[0], 0x05040100u);
    lw.y = __builtin_amdgcn_perm(x[3], x[2], 0x05040100u);
    lw.z = __builtin_amdgcn_perm(x[5], x[4], 0x05040100u);
    lw.w = __builtin_amdgcn_perm(x[7], x[6], 0x05040100u);
    hi = __builtin_bit_cast(v8s, hw);
    lo = __builtin_bit_cast(v8s, lw);
}

#define MFMA16 __builtin_amdgcn_mfma_f32_16x16x32_bf16

// One 16x16 tile at (rb,cb) of: BCOL ? P*Q : P*Q^T, K=64, split-bf16.
// A-frag: rows of P. B-frag: BCOL ? cols of Q : rows of Q.
template<bool BCOL>
__device__ __forceinline__ v4f tile16(const unsigned* __restrict__ P,
                                      const unsigned* __restrict__ Q,
                                      int rb, int cb, int lane) {
    const int nh = lane & 15, qd = lane >> 4;
    v4f a0 = {0, 0, 0, 0}, a1 = {0, 0, 0, 0};
    #pragma unroll
    for (int kk = 0; kk < 2; ++kk) {
        const int kc = kk * 32 + qd * 8;
        v8s ph, pl, qh, ql;
        load_frag(P + swz(rb + nh, kc), ph, pl);
        if constexpr (BCOL) load_col_frag(Q, cb + nh, kc, qh, ql);
        else                load_frag(Q + swz(cb + nh, kc), qh, ql);
        a0 = MFMA16(ph, qh, a0, 0, 0, 0);
        a1 = MFMA16(ph, ql, a1, 0, 0, 0);
        a1 = MFMA16(pl, qh, a1, 0, 0, 0);
    }
    return a0 + a1;
}

__launch_bounds__(1024)
__global__ void krylov_kernel(const float* __restrict__ A,
                              const float* __restrict__ Bv,
                              const float* __restrict__ Cv,
                              const float* __restrict__ logdt,
                              float* __restrict__ out)
{
    const int h    = blockIdx.x;
    const int tid  = threadIdx.x;
    const int lane = tid & 63;
    const int w    = tid >> 6;
    const int nh   = lane & 15, qd = lane >> 4;
    const int rb   = (w >> 2) * 16, cb = (w & 3) * 16;

    // W0: S -> ladder ping/pong. W1: Dt -> X -> ping/pong.
    // W2: T0/T2 -> Vt. W3: T1/T3 -> Ut.
    __shared__ __align__(16) unsigned W0[64 * STRU], W1[64 * STRU],
                                      W2[64 * STRU], W3[64 * STRU];
    __shared__ float Bl[64], Cl[64], tmv[64];

    const float dt  = expf(logdt[h]);
    const float c   = 0.5f * dt;
    const float al  = 1.0f + 0.5f * c;
    const float sd2 = (c * c) / (al * al);   // Dt = sd2 * S^2
    const float c1  = 2.0f / al;             // X = c1*T + c2*(S T) - I
    const float c2  = 2.0f * c / (al * al);
    const float k1  = dt / al;               // dB = k1*(T B) + k2*(S (T B))
    const float k2  = dt * c / (al * al);

    const float* Ah = A + (size_t)h * 4096;

    // ---- P0: pack S = A + 0.5I -> W0 (swizzled); load B, C ----
    {
        const int rr = tid >> 4, c0 = (tid & 15) * 4;
        float4 v = *(const float4*)(Ah + rr * 64 + c0);
        if (rr == c0 + 0) v.x += 0.5f;
        if (rr == c0 + 1) v.y += 0.5f;
        if (rr == c0 + 2) v.z += 0.5f;
        if (rr == c0 + 3) v.w += 0.5f;
        uint4 pk = make_uint4(packhl(v.x), packhl(v.y), packhl(v.z), packhl(v.w));
        *(uint4*)&W0[swz(rr, c0)] = pk;
        if (tid < 64) Bl[tid] = Bv[h * 64 + tid];
        else if (tid < 128) Cl[tid - 64] = Cv[h * 64 + (tid - 64)];
    }
    __syncthreads();

    // ---- P1: Dt = sd2 * (S*S) -> W1 ; T0 = Dt + I -> W2 ----
    {
        v4f a = tile16<true>(W0, W0, rb, cb, lane);
        #pragma unroll
        for (int e = 0; e < 4; ++e) {
            const int row = rb + qd * 4 + e, col = cb + nh;
            float dv = sd2 * a[e];
            W1[swz(row, col)] = packhl(dv);
            W2[swz(row, col)] = packhl(dv + (row == col ? 1.0f : 0.0f));
        }
    }
    __syncthreads();
    // ---- P2..P4 Horner: T1 = I + Dt*T0 -> W3; T2 -> W2; T3 = T -> W3 ----
    {
        v4f a = tile16<true>(W1, W2, rb, cb, lane);
        #pragma unroll
        for (int e = 0; e < 4; ++e) {
            const int row = rb + qd * 4 + e, col = cb + nh;
            W3[swz(row, col)] = packhl(a[e] + (row == col ? 1.0f : 0.0f));
        }
    }
    __syncthreads();
    {
        v4f a = tile16<true>(W1, W3, rb, cb, lane);
        #pragma unroll
        for (int e = 0; e < 4; ++e) {
            const int row = rb + qd * 4 + e, col = cb + nh;
            W2[swz(row, col)] = packhl(a[e] + (row == col ? 1.0f : 0.0f));
        }
    }
    __syncthreads();
    {
        v4f a = tile16<true>(W1, W2, rb, cb, lane);
        #pragma unroll
        for (int e = 0; e < 4; ++e) {
            const int row = rb + qd * 4 + e, col = cb + nh;
            W3[swz(row, col)] = packhl(a[e] + (row == col ? 1.0f : 0.0f));
        }
    }
    __syncthreads();
    // ---- P5: SH = S*T; X = c1*T + c2*SH - I -> W1. Wave 0 also seeds dB. ----
    {
        v4f a = tile16<true>(W0, W3, rb, cb, lane);
        #pragma unroll
        for (int e = 0; e < 4; ++e) {
            const int row = rb + qd * 4 + e, col = cb + nh;
            float t = unpackf(W3[swz(row, col)]);
            W1[swz(row, col)] = packhl(c1 * t - (row == col ? 1.0f : 0.0f)
                                       + c2 * a[e]);
        }
        if (w == 0) {
            float acc1 = 0.0f;
            #pragma unroll
            for (int m4 = 0; m4 < 16; ++m4) {
                uint4 tv = *(const uint4*)&W3[swz(lane, 4 * m4)];
                float4 b4 = *(const float4*)&Bl[4 * m4];
                acc1 += unpackf(tv.x) * b4.x + unpackf(tv.y) * b4.y
                      + unpackf(tv.z) * b4.z + unpackf(tv.w) * b4.w;
            }
            tmv[lane] = acc1;
            __threadfence_block();
            float acc2 = 0.0f;
            #pragma unroll
            for (int m4 = 0; m4 < 16; ++m4) {
                uint4 sv = *(const uint4*)&W0[swz(lane, 4 * m4)];
                float4 t4 = *(const float4*)&tmv[4 * m4];
                acc2 += unpackf(sv.x) * t4.x + unpackf(sv.y) * t4.y
                      + unpackf(sv.z) * t4.z + unpackf(sv.w) * t4.w;
            }
            W2[swz(0, lane)] = packhl(k1 * acc1 + k2 * acc2);   // Vt row 0 = dB
        }
    }
    __syncthreads();

    // ---- fused ladder: s=0..11, X_s = dA^(2^s), cur holds X_s ----
    // squaring (s<11): X_{s+1} = X_s * X_s -> nxt          [16 tiles, all waves]
    // V-dbl (s<6):  Vt[k+j] = (X_s v_j)  = row j of Vt*X_s^T   [row-frag B]
    // U-dbl (s>=6): Ut[k+j] = (X_s^T u_j) = row j of Ut*X_s    [col-frag B]
    unsigned* cur = W1;
    unsigned* nxt = W0;
    #pragma unroll 1
    for (int s = 0; s < 12; ++s) {
        if (s < 11) {
            v4f a = tile16<true>(cur, cur, rb, cb, lane);
            #pragma unroll
            for (int e = 0; e < 4; ++e)
                nxt[swz(rb + qd * 4 + e, cb + nh)] = packhl(a[e]);
        }
        const int p2 = (s < 6) ? s : s - 6;
        const int k  = 1 << p2;
        const int ndb = (k > 16) ? 8 : 4;
        if (w < ndb) {
            const int rt = (w >> 2) * 16, tc = (w & 3) * 16;
            unsigned* Xt = (s < 6) ? W2 : W3;
            v4f a = (s < 6) ? tile16<false>(Xt, cur, rt, tc, lane)
                            : tile16<true >(Xt, cur, rt, tc, lane);
            #pragma unroll
            for (int e = 0; e < 4; ++e) {
                const int j = rt + qd * 4 + e;
                if (j < k) Xt[swz(k + j, tc + nh)] = packhl(a[e]);
            }
        }
        if (s == 0 && w == 15) W3[swz(0, lane)] = packhl(Cl[lane]);  // Ut row 0 = C
        __syncthreads();
        if (s < 11) { unsigned* t = cur; cur = nxt; nxt = t; }
    }

    // ---- final: out[h][64q + r] = sum_n Ut[q][n] * Vt[r][n] ----
    {
        v4f a = tile16<false>(W3, W2, rb, cb, lane);
        float* oh = out + (size_t)h * 4096;
        #pragma unroll
        for (int e = 0; e < 4; ++e)
            oh[(rb + qd * 4 + e) * 64 + cb + nh] = a[e];
    }
}

extern "C" void kernel_launch(void* const* d_in, const int* in_sizes, int n_in,
                              void* d_out, int out_size, void* d_ws, size_t ws_size,
                              hipStream_t stream) {
    const float* A  = (const float*)d_in[0];
    const float* B  = (const float*)d_in[1];
    const float* C  = (const float*)d_in[2];
    const float* ld = (const float*)d_in[3];
    float* out = (float*)d_out;
    const int H = in_sizes[3];   // 256 heads
    krylov_kernel<<<H, 1024, 0, stream>>>(A, B, C, ld, out);
}

// Round 7
// 79.711 us; speedup vs baseline: 1.0337x; 1.0337x over previous
//
#include <hip/hip_runtime.h>

constexpr int STRU = 68;   // row stride in u32 (272 B; rows 16B-aligned)

typedef short v8s __attribute__((ext_vector_type(8)));
typedef float v4f __attribute__((ext_vector_type(4)));

// fp32 -> packed (bf16_hi << 16) | bf16_lo. hi = truncated, lo = Dekker remainder.
__device__ __forceinline__ unsigned packhl(float x) {
    unsigned xb = __builtin_bit_cast(unsigned, x);
    unsigned hb = xb & 0xffff0000u;
    float lof = x - __builtin_bit_cast(float, hb);           // exact
    unsigned lb = __builtin_bit_cast(unsigned, lof) + 0x8000u;
    return __builtin_amdgcn_perm(xb, lb, 0x07060302u);
}

__device__ __forceinline__ float unpackf(unsigned v) {
    float h = __builtin_bit_cast(float, v & 0xffff0000u);
    float l = __builtin_bit_cast(float, v << 16);
    return h + l;
}

// 8 contiguous packed u32 (row fragment) -> hi/lo bf16x8
__device__ __forceinline__ void load_frag(const unsigned* p, v8s& hi, v8s& lo) {
    uint4 a = *(const uint4*)p;
    uint4 b = *(const uint4*)(p + 4);
    uint4 hw, lw;
    hw.x = __builtin_amdgcn_perm(a.y, a.x, 0x07060302u);
    hw.y = __builtin_amdgcn_perm(a.w, a.z, 0x07060302u);
    hw.z = __builtin_amdgcn_perm(b.y, b.x, 0x07060302u);
    hw.w = __builtin_amdgcn_perm(b.w, b.z, 0x07060302u);
    lw.x = __builtin_amdgcn_perm(a.y, a.x, 0x05040100u);
    lw.y = __builtin_amdgcn_perm(a.w, a.z, 0x05040100u);
    lw.z = __builtin_amdgcn_perm(b.y, b.x, 0x05040100u);
    lw.w = __builtin_amdgcn_perm(b.w, b.z, 0x05040100u);
    hi = __builtin_bit_cast(v8s, hw);
    lo = __builtin_bit_cast(v8s, lw);
}

#define MFMA16 __builtin_amdgcn_mfma_f32_16x16x32_bf16

// Row-strip of D = P * Q^T: rows [rb, rb+16), col-tiles [t0, t0+NT).
// A-fragment (rows rb+nh of P) loaded ONCE and shared across all NT tiles.
// Output tile t element: row = rb + 4*qd + e, col = (t0+t)*16 + nh.
template<int NT>
__device__ __forceinline__ void strip_acc(const unsigned* __restrict__ P,
                                          const unsigned* __restrict__ Q,
                                          int rb, int t0, int lane, v4f* acc) {
    const int nh = lane & 15, qd = lane >> 4;
    v8s ah[2], al[2];
    load_frag(P + (rb + nh) * STRU + qd * 8,      ah[0], al[0]);
    load_frag(P + (rb + nh) * STRU + 32 + qd * 8, ah[1], al[1]);
    v8s bh[NT][2], bl[NT][2];
    #pragma unroll
    for (int t = 0; t < NT; ++t) {
        const unsigned* qr = Q + ((t0 + t) * 16 + nh) * STRU;
        load_frag(qr + qd * 8,      bh[t][0], bl[t][0]);
        load_frag(qr + 32 + qd * 8, bh[t][1], bl[t][1]);
    }
    #pragma unroll
    for (int t = 0; t < NT; ++t) {
        v4f a0 = {0, 0, 0, 0}, a1 = {0, 0, 0, 0};
        #pragma unroll
        for (int kk = 0; kk < 2; ++kk) {
            a0 = MFMA16(ah[kk], bh[t][kk], a0, 0, 0, 0);
            a1 = MFMA16(ah[kk], bl[t][kk], a1, 0, 0, 0);
            a1 = MFMA16(al[kk], bh[t][kk], a1, 0, 0, 0);
        }
        acc[t] = a0 + a1;
    }
}

__launch_bounds__(512)
__global__ void krylov_kernel(const float* __restrict__ A,
                              const float* __restrict__ Bv,
                              const float* __restrict__ Cv,
                              const float* __restrict__ logdt,
                              float* __restrict__ out)
{
    const int h    = blockIdx.x;
    const int tid  = threadIdx.x;
    const int lane = tid & 63;
    const int w    = tid >> 6;
    const int nh   = lane & 15, qd = lane >> 4;

    // B0: X-ping. B1: S, then X-pong. B2: XT-ping. B3: D, then XT-pong.
    // B4: T0/T2, then Vt. B5: T1/T, then Ut.
    __shared__ __align__(16) unsigned B0[64 * STRU], B1[64 * STRU], B2[64 * STRU],
                                      B3[64 * STRU], B4[64 * STRU], B5[64 * STRU];
    __shared__ float Bl[64], Cl[64], tmv[64];

    const float dt  = expf(logdt[h]);
    const float c   = 0.5f * dt;
    const float al  = 1.0f + 0.5f * c;
    const float sd2 = (c * c) / (al * al);   // D = sd2 * S^2 = -sd2 * (S S^T)
    const float c1  = 2.0f / al;             // X = c1*T + c2*(S T) - I
    const float c2  = 2.0f * c / (al * al);
    const float k1  = dt / al;               // dB = k1*(T B) + k2*(S (T B))
    const float k2  = dt * c / (al * al);

    const float* Ah = A + (size_t)h * 4096;

    // ---- P0: pack S = A + 0.5I -> B1; load B, C ----
    for (int idx = tid; idx < 1024; idx += 512) {
        const int rr = idx >> 4, c0 = (idx & 15) * 4;
        float4 v = *(const float4*)(Ah + rr * 64 + c0);
        if (rr == c0 + 0) v.x += 0.5f;
        if (rr == c0 + 1) v.y += 0.5f;
        if (rr == c0 + 2) v.z += 0.5f;
        if (rr == c0 + 3) v.w += 0.5f;
        uint4 pk = make_uint4(packhl(v.x), packhl(v.y), packhl(v.z), packhl(v.w));
        *(uint4*)&B1[rr * STRU + c0] = pk;
    }
    if (tid < 64) Bl[tid] = Bv[h * 64 + tid];
    else if (tid < 128) Cl[tid - 64] = Cv[h * 64 + (tid - 64)];
    __syncthreads();

    const int hrb = 16 * (w & 3), ht0 = 2 * (w >> 2);   // half-strip for 8 waves

    // ---- P1: D = -sd2*(S*S^T) -> B3 ; T0 = D + I -> B4 ----
    {
        v4f a[2]; strip_acc<2>(B1, B1, hrb, ht0, lane, a);
        #pragma unroll
        for (int t = 0; t < 2; ++t)
            #pragma unroll
            for (int e = 0; e < 4; ++e) {
                const int row = hrb + 4 * qd + e, col = (ht0 + t) * 16 + nh;
                float dv = -sd2 * a[t][e];
                B3[row * STRU + col] = packhl(dv);
                B4[row * STRU + col] = packhl(dv + (row == col ? 1.0f : 0.0f));
            }
    }
    __syncthreads();
    // ---- P2: T1 = I + D*T0 -> B5 ----
    {
        v4f a[2]; strip_acc<2>(B3, B4, hrb, ht0, lane, a);
        #pragma unroll
        for (int t = 0; t < 2; ++t)
            #pragma unroll
            for (int e = 0; e < 4; ++e) {
                const int row = hrb + 4 * qd + e, col = (ht0 + t) * 16 + nh;
                B5[row * STRU + col] = packhl(a[t][e] + (row == col ? 1.0f : 0.0f));
            }
    }
    __syncthreads();
    // ---- P3: T2 = I + D*T1 -> B4 ----
    {
        v4f a[2]; strip_acc<2>(B3, B5, hrb, ht0, lane, a);
        #pragma unroll
        for (int t = 0; t < 2; ++t)
            #pragma unroll
            for (int e = 0; e < 4; ++e) {
                const int row = hrb + 4 * qd + e, col = (ht0 + t) * 16 + nh;
                B4[row * STRU + col] = packhl(a[t][e] + (row == col ? 1.0f : 0.0f));
            }
    }
    __syncthreads();
    // ---- P4: T = I + D*T2 -> B5 ----
    {
        v4f a[2]; strip_acc<2>(B3, B4, hrb, ht0, lane, a);
        #pragma unroll
        for (int t = 0; t < 2; ++t)
            #pragma unroll
            for (int e = 0; e < 4; ++e) {
                const int row = hrb + 4 * qd + e, col = (ht0 + t) * 16 + nh;
                B5[row * STRU + col] = packhl(a[t][e] + (row == col ? 1.0f : 0.0f));
            }
    }
    __syncthreads();
    // ---- P5: w0-3: SH = S*T; X0 = c1*T + c2*SH - I -> B0, XT0 -> B2.
    //          w4: dB = k1*(T B) + k2*(S (T B)) -> Vt(B4) row 0. ----
    if (w < 4) {
        v4f a[4]; strip_acc<4>(B1, B5, 16 * w, 0, lane, a);
        #pragma unroll
        for (int t = 0; t < 4; ++t)
            #pragma unroll
            for (int e = 0; e < 4; ++e) {
                const int row = 16 * w + 4 * qd + e, col = t * 16 + nh;
                float tv = unpackf(B5[row * STRU + col]);
                float base = c1 * tv - (row == col ? 1.0f : 0.0f);
                float sv   = c2 * a[t][e];
                B0[row * STRU + col] = packhl(base + sv);
                B2[row * STRU + col] = packhl(base - sv);
            }
    } else if (w == 4) {
        float acc1 = 0.0f;
        #pragma unroll
        for (int m4 = 0; m4 < 16; ++m4) {
            uint4 tv = *(const uint4*)&B5[lane * STRU + 4 * m4];
            float4 b4 = *(const float4*)&Bl[4 * m4];
            acc1 += unpackf(tv.x) * b4.x + unpackf(tv.y) * b4.y
                  + unpackf(tv.z) * b4.z + unpackf(tv.w) * b4.w;
        }
        tmv[lane] = acc1;
        __threadfence_block();
        float acc2 = 0.0f;
        #pragma unroll
        for (int m4 = 0; m4 < 16; ++m4) {
            uint4 sv = *(const uint4*)&B1[lane * STRU + 4 * m4];
            float4 t4 = *(const float4*)&tmv[4 * m4];
            acc2 += unpackf(sv.x) * t4.x + unpackf(sv.y) * t4.y
                  + unpackf(sv.z) * t4.z + unpackf(sv.w) * t4.w;
        }
        B4[lane] = packhl(k1 * acc1 + k2 * acc2);   // Vt row 0 = dB
    }
    __syncthreads();

    // ---- ladder: iter p: bX = X_p = dA^(2^p).
    //   w0-3 (p<11): sq X_p -> X_{p+1} into bN (and transpose into bNT).
    //   w4-7: p<6: V-dbl(k=2^p) on Vt(B4) with bX;  p>=6: U-dbl(k=2^{p-6})
    //         on Ut(B5) with bXT. Lag-safe: dbl reads bX/bXT, sq writes bN/bNT.
    unsigned *bX = B0, *bXT = B2, *bN = B1, *bNT = B3;
    #pragma unroll 1
    for (int p = 0; p < 12; ++p) {
        if (w < 4) {
            if (p < 11) {
                v4f a[4]; strip_acc<4>(bX, bXT, 16 * w, 0, lane, a);
                #pragma unroll
                for (int t = 0; t < 4; ++t) {
                    uint4 tp;
                    #pragma unroll
                    for (int e = 0; e < 4; ++e) {
                        unsigned pk = packhl(a[t][e]);
                        bN[(16 * w + 4 * qd + e) * STRU + t * 16 + nh] = pk;
                        ((unsigned*)&tp)[e] = pk;
                    }
                    *(uint4*)&bNT[(t * 16 + nh) * STRU + 16 * w + 4 * qd] = tp;
                }
            }
        } else {
            const bool isV = (p < 6);
            const int  k   = 1 << (isV ? p : p - 6);
            unsigned*  Kt  = isV ? B4 : B5;
            const unsigned* M = isV ? bX : bXT;
            const int ntr = (k + 15) >> 4;
            for (int tr = 0; tr < ntr; ++tr) {
                v4f a[1]; strip_acc<1>(Kt, M, tr * 16, w - 4, lane, a);
                #pragma unroll
                for (int e = 0; e < 4; ++e) {
                    const int j = tr * 16 + 4 * qd + e;
                    if (j < k) Kt[(k + j) * STRU + (w - 4) * 16 + nh] = packhl(a[0][e]);
                }
            }
            if (p == 0 && w == 4) B5[lane] = packhl(Cl[lane]);   // Ut row 0 = C
        }
        __syncthreads();
        if (p < 11) {
            unsigned* t0_ = bX;  bX  = bN;  bN  = t0_;
            t0_ = bXT; bXT = bNT; bNT = t0_;
        }
    }

    // ---- final: out[h][64q + r] = sum_n Ut[q][n] * Vt[r][n]  (8 half-strips) ----
    {
        v4f a[2]; strip_acc<2>(B5, B4, hrb, ht0, lane, a);
        float* oh = out + (size_t)h * 4096;
        #pragma unroll
        for (int t = 0; t < 2; ++t)
            #pragma unroll
            for (int e = 0; e < 4; ++e)
                oh[(hrb + 4 * qd + e) * 64 + (ht0 + t) * 16 + nh] = a[t][e];
    }
}

extern "C" void kernel_launch(void* const* d_in, const int* in_sizes, int n_in,
                              void* d_out, int out_size, void* d_ws, size_t ws_size,
                              hipStream_t stream) {
    const float* A  = (const float*)d_in[0];
    const float* B  = (const float*)d_in[1];
    const float* C  = (const float*)d_in[2];
    const float* ld = (const float*)d_in[3];
    float* out = (float*)d_out;
    const int H = in_sizes[3];   // 256 heads
    krylov_kernel<<<H, 512, 0, stream>>>(A, B, C, ld, out);
}